// Round 10
// baseline (10111.552 us; speedup 1.0000x reference)
//
#include <hip/hip_runtime.h>

// LSTM: H=1024, B=1024, S=128 (T=127 steps), E=6, V=3, C=10.
// All float tensors FP32; x int32; output FP32 (1024 x 10).
// R10: persistent kernel via PLAIN launch (cooperative API never executed in
// R9 -> bias-only output signature) + hierarchical hand-rolled epoch barrier
// (8 group ctrs + 1 global; R5's failure re-audited: it was the tid<384
// Q-slice bug in a 256-thread block, NOT the barrier). 256 blocks (1/CU,
// co-resident by construction), tile 16 rows x 4 gates x 256 cols (nt=4),
// weights k<448 in LDS once, rest streamed from L2; c in VGPRs for all steps;
// logits fused after the final barrier. Guard valve so failure != hang.
constexpr int kH = 1024;
constexpr int kB = 1024;
constexpr int kS = 128;
constexpr int kT = 127;
constexpr int kE = 6;
constexpr int kV = 3;
constexpr int kC = 10;
constexpr int kKL = 14;          // k0 chunks (of 32) resident in LDS: k < 448

typedef short s16x8 __attribute__((ext_vector_type(8)));
typedef short s16x4 __attribute__((ext_vector_type(4)));
typedef float f32x4 __attribute__((ext_vector_type(4)));
typedef unsigned short u16;

__device__ __forceinline__ float b2f(u16 u) {
    return __uint_as_float(((unsigned)u) << 16);
}
__device__ __forceinline__ u16 f2b(float f) {
    unsigned u = __float_as_uint(f);
    return (u16)((u + 0x7FFFu + ((u >> 16) & 1u)) >> 16);   // RNE
}
__device__ __forceinline__ float sigmoid_fast(float x) {
    return 1.0f / (1.0f + __expf(-x));
}
__device__ __forceinline__ float tanh_fast(float x) {
    return 2.0f / (1.0f + __expf(-2.0f * x)) - 1.0f;
}
__device__ __forceinline__ float clamp30(float x) {
    return fminf(fmaxf(x, -30.0f), 30.0f);
}

__device__ __forceinline__ void async_copy16(const u16* g, u16* l) {
    __builtin_amdgcn_global_load_lds(
        (const __attribute__((address_space(1))) void*)g,
        (__attribute__((address_space(3))) void*)l, 16, 0, 0);
}

// ---------------------------------------------------------------------------
// Prep 1: weights fp32 -> bf16 frag-major:
//   flat short idx = (((by*32 + k0)*4 + g)*64 + lane)*8 + j
//   = W_g[by*16 + (lane&15)][k0*32 + (lane>>4)*8 + j]
// ---------------------------------------------------------------------------
__global__ __launch_bounds__(256) void prep_weights(
    const float* __restrict__ Wgh, const float* __restrict__ Wih,
    const float* __restrict__ Wfh, const float* __restrict__ Woh,
    short* __restrict__ wsw)
{
    unsigned grp = blockIdx.x * 256 + threadIdx.x;    // 0 .. 2^19-1
    const int lane = grp & 63;
    const int lm   = lane & 15;
    const int quad = lane >> 4;
    const int g    = (grp >> 6) & 3;
    const int k0   = (grp >> 8) & 31;
    const int by   = grp >> 13;                       // 0..63
    const float* src = (g == 0) ? Wgh : (g == 1) ? Wih : (g == 2) ? Wfh : Woh;
    const int row = by * 16 + lm;
    const int k   = k0 * 32 + quad * 8;
    f32x4 v0 = *(const f32x4*)(src + (size_t)row * kH + k);
    f32x4 v1 = *(const f32x4*)(src + (size_t)row * kH + k + 4);
    s16x8 o;
#pragma unroll
    for (int j = 0; j < 4; ++j) o[j] = (short)f2b(v0[j]);
#pragma unroll
    for (int j = 0; j < 4; ++j) o[4 + j] = (short)f2b(v1[j]);
    *(s16x8*)(wsw + (size_t)grp * 8) = o;
}

// ---------------------------------------------------------------------------
// Prep 2: transpose h0 (H,B) fp32 -> hA (B,H) bf16.
// ---------------------------------------------------------------------------
__global__ __launch_bounds__(1024) void prep_h(
    const float* __restrict__ h0, u16* __restrict__ hA)
{
    __shared__ float th[32][33];
    int b = blockIdx.x * 32 + threadIdx.x;
    int h = blockIdx.y * 32 + threadIdx.y;
    th[threadIdx.y][threadIdx.x] = h0[(size_t)h * kB + b];
    __syncthreads();
    int ob = blockIdx.x * 32 + threadIdx.y;
    int oh = blockIdx.y * 32 + threadIdx.x;
    hA[(size_t)ob * kH + oh] = f2b(th[threadIdx.x][threadIdx.y]);
}

// ---------------------------------------------------------------------------
// Hierarchical epoch barrier. bar[g*32] = group ctr (g=0..7, 128 B apart),
// bar[256] = global ctr. Group g = blk&7 (XCD-heuristic; correctness doesn't
// depend on the mapping). Leaders: blk < 8. Monotone counters, never reset.
// ---------------------------------------------------------------------------
__device__ __forceinline__ void gbar(unsigned* bar, int g, bool leader, int epoch) {
    __threadfence();            // release: this block's h writes visible
    __syncthreads();            // all waves done with this step
    if (threadIdx.x == 0) {
        __hip_atomic_fetch_add(&bar[g * 32], 1u, __ATOMIC_RELEASE,
                               __HIP_MEMORY_SCOPE_AGENT);
        if (leader) {
            const unsigned gt = 32u * (unsigned)epoch;
            int gc = 0;
            while (__hip_atomic_load(&bar[g * 32], __ATOMIC_ACQUIRE,
                                     __HIP_MEMORY_SCOPE_AGENT) < gt)
                if (++gc > (1 << 18)) break;
            __hip_atomic_fetch_add(&bar[256], 1u, __ATOMIC_RELEASE,
                                   __HIP_MEMORY_SCOPE_AGENT);
        }
        const unsigned t8 = 8u * (unsigned)epoch;
        int gc = 0;
        while (__hip_atomic_load(&bar[256], __ATOMIC_ACQUIRE,
                                 __HIP_MEMORY_SCOPE_AGENT) < t8)
            if (++gc > (1 << 18)) break;
    }
    __syncthreads();
    __builtin_amdgcn_fence(__ATOMIC_ACQUIRE, "agent");   // all threads acquire
}

// ---------------------------------------------------------------------------
// Persistent LSTM + fused logits. 256 blocks x 256 thr (1 block/CU, 4 waves).
// bx = blk>>6 (col group of 256), j = blk&63, by = (j&7)*8 + (j>>3).
// Wave w: cols [bx*256 + w*64, +64) (nt=4), rows [by*16,+16), 4 gates.
// ---------------------------------------------------------------------------
__global__ __launch_bounds__(256, 1) void lstm_persist(
    const short* __restrict__ wsw, const int* __restrict__ x,
    const float* __restrict__ c0g,
    const float* __restrict__ Wgx, const float* __restrict__ Wix,
    const float* __restrict__ Wfx, const float* __restrict__ Wox,
    const float* __restrict__ bg,  const float* __restrict__ bi,
    const float* __restrict__ bf_, const float* __restrict__ bo,
    const float* __restrict__ emb,
    u16* __restrict__ hA, u16* __restrict__ hB,
    unsigned* __restrict__ bar,
    const float* __restrict__ Wph, const float* __restrict__ bp,
    float* __restrict__ out)
{
    __shared__ short wl[kKL * 4 * 64 * 8];   // 57344 B: k0<14, frag-major
    __shared__ float qs[4][16][4];           // 1 KB

    const int tid  = threadIdx.x;
    const int lane = tid & 63;
    const int wave = tid >> 6;
    const int lm   = lane & 15;
    const int quad = lane >> 4;
    const int blk  = blockIdx.x;
    const int bx   = blk >> 6;
    const int j    = blk & 63;
    const int by   = (j & 7) * 8 + (j >> 3);
    const int r0   = by * 16;
    const int cw   = bx * 256 + wave * 64;
    const int koff = quad * 8;
    const int grpid  = blk & 7;
    const bool leader = (blk < 8);

    const short* wswblk = wsw + (size_t)by * 65536;

    // --- stage LDS-resident weights (56 KB, once) ---
#pragma unroll
    for (int rr = 0; rr < kKL; ++rr) {
        const int ub = wave * (kKL * 512) + rr * 512;   // shorts
        async_copy16((const u16*)(wswblk + ub) + lane * 8, (u16*)&wl[ub]);
    }

    // --- Q slice: qs[g][r][v], 192 workers (<= 256: R5's fatal bug fixed) ---
    if (tid < 192) {
        int g = tid / 48, rem = tid % 48, r = rem / 3, v = rem % 3;
        const float* Wx = (g == 0) ? Wgx : (g == 1) ? Wix : (g == 2) ? Wfx : Wox;
        const float* bb = (g == 0) ? bg  : (g == 1) ? bi  : (g == 2) ? bf_ : bo;
        int hr = r0 + r;
        float s = bb[hr];
#pragma unroll
        for (int e = 0; e < kE; ++e) s += Wx[hr * kE + e] * emb[v * kE + e];
        qs[g][r][v] = s;
    }

    // --- c state into registers (persists across all 127 steps) ---
    float creg[4][4];
#pragma unroll
    for (int nt = 0; nt < 4; ++nt)
#pragma unroll
        for (int reg = 0; reg < 4; ++reg)
            creg[nt][reg] =
                c0g[(size_t)(r0 + quad * 4 + reg) * kB + (cw + nt * 16 + lm)];

    asm volatile("s_waitcnt vmcnt(0)" ::: "memory");
    __syncthreads();

    auto loadA = [&](int s, s16x8 d[4]) {
        if (s < kKL) {
#pragma unroll
            for (int g = 0; g < 4; ++g)
                d[g] = *(const s16x8*)&wl[((s * 4 + g) * 64 + lane) * 8];
        } else {
#pragma unroll
            for (int g = 0; g < 4; ++g)
                d[g] = *(const s16x8*)(wswblk + (size_t)(s * 4 + g) * 512 + lane * 8);
        }
    };

#pragma unroll 1
    for (int t = 0; t < kT; ++t) {
        const short* hin = (t & 1) ? (const short*)hB : (const short*)hA;
        u16* hout = (t & 1) ? hA : hB;

        int vv[4];
#pragma unroll
        for (int nt = 0; nt < 4; ++nt) {
            int v = x[(size_t)(cw + nt * 16 + lm) * kS + t];
            vv[nt] = (v < 0) ? 0 : (v > kV - 1) ? (kV - 1) : v;
        }

        f32x4 acc[4][4];
        const f32x4 zero = {0.f, 0.f, 0.f, 0.f};
#pragma unroll
        for (int g = 0; g < 4; ++g)
#pragma unroll
            for (int nt = 0; nt < 4; ++nt) acc[g][nt] = zero;

        auto loadB = [&](int s, s16x8 d[4]) {
#pragma unroll
            for (int nt = 0; nt < 4; ++nt)
                d[nt] = *(const s16x8*)(hin + (size_t)(cw + nt * 16 + lm) * kH +
                                        s * 32 + koff);
        };

        // depth-3 ring prefetch over 32 K-chunks
        s16x8 ar[3][4], br[3][4];
        loadA(0, ar[0]); loadB(0, br[0]);
        loadA(1, ar[1]); loadB(1, br[1]);
#pragma unroll
        for (int k0 = 0; k0 < 32; ++k0) {
            const int cur = k0 % 3;
            if (k0 + 2 < 32) {
                const int nxt = (k0 + 2) % 3;
                loadA(k0 + 2, ar[nxt]);
                loadB(k0 + 2, br[nxt]);
            }
#pragma unroll
            for (int g = 0; g < 4; ++g)
#pragma unroll
                for (int nt = 0; nt < 4; ++nt)
                    acc[g][nt] = __builtin_amdgcn_mfma_f32_16x16x32_bf16(
                        ar[cur][g], br[cur][nt], acc[g][nt], 0, 0, 0);
        }

        // Epilogue. C/D layout: col = lane&15, row = quad*4+reg (m89/m91).
#pragma unroll
        for (int nt = 0; nt < 4; ++nt) {
            const int col = cw + nt * 16 + lm;
            s16x4 hnew;
#pragma unroll
            for (int reg = 0; reg < 4; ++reg) {
                const int rl = quad * 4 + reg;
                float pg = clamp30(acc[0][nt][reg] + qs[0][rl][vv[nt]]);
                float pi = clamp30(acc[1][nt][reg] + qs[1][rl][vv[nt]]);
                float pf = clamp30(acc[2][nt][reg] + qs[2][rl][vv[nt]]);
                float po = clamp30(acc[3][nt][reg] + qs[3][rl][vv[nt]]);
                float gg = tanh_fast(pg);
                float ii = sigmoid_fast(pi);
                float ff = sigmoid_fast(pf);
                float oo = sigmoid_fast(po);
                float c2 = gg * ii + creg[nt][reg] * ff;
                c2 = fminf(fmaxf(c2, -200.0f), 200.0f);
                creg[nt][reg] = c2;
                hnew[reg] = (short)f2b(tanh_fast(c2) * oo);
            }
            *(s16x4*)(hout + (size_t)col * kH + r0 + quad * 4) = hnew;
        }

        gbar(bar, grpid, leader, t + 1);   // epochs 1..127
    }

    // --- fused logits + log_softmax (final h in hB; t=126 even) ---
    {
        const int b = blk * 4 + wave;
        const u16* hp = hB + (size_t)b * kH + lane * 16;
        float hf[16];
#pragma unroll
        for (int jj = 0; jj < 16; ++jj) hf[jj] = b2f(hp[jj]);

        float p[kC];
#pragma unroll
        for (int cls = 0; cls < kC; ++cls) {
            const float* wp = Wph + (size_t)cls * kH + lane * 16;
            float s = 0.f;
#pragma unroll
            for (int jj = 0; jj < 16; ++jj) s += hf[jj] * wp[jj];
#pragma unroll
            for (int off = 1; off < 64; off <<= 1) s += __shfl_xor(s, off, 64);
            p[cls] = fminf(fmaxf(s + bp[cls], -1.0e4f), 1.0e4f);
        }

        float m = p[0];
#pragma unroll
        for (int cls = 1; cls < kC; ++cls) m = fmaxf(m, p[cls]);
        float se = 0.f;
#pragma unroll
        for (int cls = 0; cls < kC; ++cls) se += __expf(p[cls] - m);
        float l = m + __logf(se);

        if (lane < kC) {
            float myp = p[0];
#pragma unroll
            for (int cls = 1; cls < kC; ++cls)
                if (lane == cls) myp = p[cls];
            out[(size_t)b * kC + lane] = myp - l;
        }
    }
}

// ---------------------------------------------------------------------------
extern "C" void kernel_launch(void* const* d_in, const int* in_sizes, int n_in,
                              void* d_out, int out_size, void* d_ws, size_t ws_size,
                              hipStream_t stream)
{
    const int*   x   = (const int*)  d_in[0];
    const float* emb = (const float*)d_in[1];
    const float* Wgx = (const float*)d_in[2];
    const float* Wgh = (const float*)d_in[3];
    const float* bg  = (const float*)d_in[4];
    const float* Wix = (const float*)d_in[5];
    const float* Wih = (const float*)d_in[6];
    const float* bi  = (const float*)d_in[7];
    const float* Wfx = (const float*)d_in[8];
    const float* Wfh = (const float*)d_in[9];
    const float* bf_ = (const float*)d_in[10];
    const float* Wox = (const float*)d_in[11];
    const float* Woh = (const float*)d_in[12];
    const float* bo  = (const float*)d_in[13];
    const float* Wph = (const float*)d_in[14];
    const float* bp  = (const float*)d_in[15];
    const float* h0  = (const float*)d_in[16];
    const float* c0  = (const float*)d_in[17];

    char* ws = (char*)d_ws;
    unsigned* bar = (unsigned*)ws;                    // 4 KB (uses 1028 B)
    u16*   hA  = (u16*)(ws + 4096);                   // 2 MB
    u16*   hB  = hA + (size_t)kB * kH;                // 2 MB
    short* wsw = (short*)(hB + (size_t)kB * kH);      // 8 MB

    hipMemsetAsync(bar, 0, 4096, stream);             // capture-legal
    prep_weights<<<dim3(2048), dim3(256), 0, stream>>>(Wgh, Wih, Wfh, Woh, wsw);
    prep_h<<<dim3(kB / 32, kH / 32), dim3(32, 32), 0, stream>>>(h0, hA);

    lstm_persist<<<dim3(256), dim3(256), 0, stream>>>(
        wsw, x, c0, Wgx, Wix, Wfx, Wox, bg, bi, bf_, bo, emb,
        hA, hB, bar, Wph, bp, (float*)d_out);
}

// Round 12
// 2932.342 us; speedup vs baseline: 3.4483x; 3.4483x over previous
//
#include <hip/hip_runtime.h>

// LSTM: H=1024, B=1024, S=128 (T=127 steps), E=6, V=3, C=10.
// All float tensors FP32; x int32; output FP32 (1024 x 10).
// R12 = R8 skeleton (multi-launch; persistent/barrier line abandoned after
// R10/R11: coherent spins = per-poll L2 invalidate, relaxed spins = no
// cross-XCD visibility). Targeted fixes vs R8:
//  1) depth-6 free-running b-ring (h reads are guaranteed L2-misses, ~400-900
//     cyc; R8's depth-1 prefetch exposed ~300-700 cyc x 32 k0 per wave),
//  2) x/c/gate-const loads hoisted to kernel start; Q repacked as f32x4 per
//     (gate,row4,vocab) so the epilogue has zero global loads.
constexpr int kH = 1024;
constexpr int kB = 1024;
constexpr int kS = 128;
constexpr int kT = 127;
constexpr int kE = 6;
constexpr int kV = 3;
constexpr int kC = 10;

typedef short s16x8 __attribute__((ext_vector_type(8)));
typedef short s16x4 __attribute__((ext_vector_type(4)));
typedef float f32x4 __attribute__((ext_vector_type(4)));
typedef unsigned short u16;

__device__ __forceinline__ float b2f(u16 u) {
    return __uint_as_float(((unsigned)u) << 16);
}
__device__ __forceinline__ u16 f2b(float f) {
    unsigned u = __float_as_uint(f);
    return (u16)((u + 0x7FFFu + ((u >> 16) & 1u)) >> 16);   // RNE
}
__device__ __forceinline__ float sigmoid_fast(float x) {
    return 1.0f / (1.0f + __expf(-x));
}
__device__ __forceinline__ float tanh_fast(float x) {
    return 2.0f / (1.0f + __expf(-2.0f * x)) - 1.0f;
}
__device__ __forceinline__ float clamp30(float x) {
    return fminf(fmaxf(x, -30.0f), 30.0f);
}

__device__ __forceinline__ void async_copy16(const u16* g, u16* l) {
    __builtin_amdgcn_global_load_lds(
        (const __attribute__((address_space(1))) void*)g,
        (__attribute__((address_space(3))) void*)l, 16, 0, 0);
}

// ---------------------------------------------------------------------------
// Prep 1: weights fp32 -> bf16, frag-major (identical to R8):
//   grp = (((by*4 + kc)*4 + g)*8 + k0)*64 + lane
//   wsw[grp*8 + j] = W_g[by*16 + (lane&15)][kc*256 + k0*32 + (lane>>4)*8 + j]
// ---------------------------------------------------------------------------
__global__ __launch_bounds__(256) void prep_weights(
    const float* __restrict__ Wgh, const float* __restrict__ Wih,
    const float* __restrict__ Wfh, const float* __restrict__ Woh,
    u16* __restrict__ wsw)
{
    unsigned grp = blockIdx.x * 256 + threadIdx.x;    // 0 .. 2^19-1
    const int lane = grp & 63;
    const int lm   = lane & 15;
    const int quad = lane >> 4;
    const int k0   = (grp >> 6) & 7;
    const int g    = (grp >> 9) & 3;
    const int kc   = (grp >> 11) & 3;
    const int by   = grp >> 13;                       // 0..63
    const float* src = (g == 0) ? Wgh : (g == 1) ? Wih : (g == 2) ? Wfh : Woh;
    const int row = by * 16 + lm;
    const int k   = kc * 256 + k0 * 32 + quad * 8;
    f32x4 v0 = *(const f32x4*)(src + (size_t)row * kH + k);
    f32x4 v1 = *(const f32x4*)(src + (size_t)row * kH + k + 4);
    s16x8 o;
#pragma unroll
    for (int j = 0; j < 4; ++j) o[j] = (short)f2b(v0[j]);
#pragma unroll
    for (int j = 0; j < 4; ++j) o[4 + j] = (short)f2b(v1[j]);
    *(s16x8*)(wsw + (size_t)grp * 8) = o;
}

// ---------------------------------------------------------------------------
// Prep 2: transpose h0 (H,B) fp32 -> hA (B,H) bf16; c0 (H,B) -> cT (B,H) fp32.
// ---------------------------------------------------------------------------
__global__ __launch_bounds__(1024) void prep_hc(
    const float* __restrict__ h0, const float* __restrict__ c0,
    u16* __restrict__ hA, float* __restrict__ cT)
{
    __shared__ float th[32][33];
    __shared__ float tc[32][33];
    int b = blockIdx.x * 32 + threadIdx.x;
    int h = blockIdx.y * 32 + threadIdx.y;
    th[threadIdx.y][threadIdx.x] = h0[(size_t)h * kB + b];
    tc[threadIdx.y][threadIdx.x] = c0[(size_t)h * kB + b];
    __syncthreads();
    int ob = blockIdx.x * 32 + threadIdx.y;
    int oh = blockIdx.y * 32 + threadIdx.x;
    hA[(size_t)ob * kH + oh] = f2b(th[threadIdx.x][threadIdx.y]);
    cT[(size_t)ob * kH + oh] = tc[threadIdx.x][threadIdx.y];
}

// ---------------------------------------------------------------------------
// Prep 3: gate constants repacked as f32x4:
//   Qp[((g*256 + hr4)*4 + v)*4 + reg] = b_g[hr4*4+reg] + sum_e W_gx[.,e]*emb[v,e]
// One thread per (g, hr4, v): 4096 threads. v=3 lane = 0 (padding).
// ---------------------------------------------------------------------------
__global__ __launch_bounds__(256) void prep_q(
    const float* __restrict__ Wgx, const float* __restrict__ Wix,
    const float* __restrict__ Wfx, const float* __restrict__ Wox,
    const float* __restrict__ bg,  const float* __restrict__ bi,
    const float* __restrict__ bf_, const float* __restrict__ bo,
    const float* __restrict__ emb, float* __restrict__ Qp)
{
    int tid = blockIdx.x * blockDim.x + threadIdx.x;   // 0..4095
    if (tid >= 4096) return;
    int g   = tid >> 10;
    int hr4 = (tid & 1023) >> 2;
    int v   = tid & 3;
    const float* Wx = (g == 0) ? Wgx : (g == 1) ? Wix : (g == 2) ? Wfx : Wox;
    const float* bb = (g == 0) ? bg  : (g == 1) ? bi  : (g == 2) ? bf_ : bo;
    f32x4 o;
#pragma unroll
    for (int reg = 0; reg < 4; ++reg) {
        int row = hr4 * 4 + reg;
        float s = bb[row];
        if (v < kV) {
#pragma unroll
            for (int e = 0; e < kE; ++e) s += Wx[row * kE + e] * emb[v * kE + e];
        }
        o[reg] = s;
    }
    *(f32x4*)(Qp + (size_t)tid * 4) = o;
}

// ---------------------------------------------------------------------------
// One LSTM timestep. Grid 512 x 256 thr (2 blocks/CU). Block tile: 16 h-rows
// x 4 gates x 128 cols; wave w: cols [bx*128+32w,+32) (nt=2).
// XCD swizzle: xcd=blk&7, slot=blk>>3, by=xcd*8+(slot&7), bx=slot>>3.
// Weights: 4 K-chunks of 256 staged to LDS (2x32 KB double buffer).
// b-operand: depth-6 free-running register ring from global h.
// ---------------------------------------------------------------------------
__global__ __launch_bounds__(256, 2) void lstm_step(
    const u16* __restrict__ wsw, const float* __restrict__ Qp,
    const int* __restrict__ x, int t,
    const short* __restrict__ hin, u16* __restrict__ hout,
    float* __restrict__ cT)
{
    __shared__ u16 wlds[2][16384];   // 2 x 32 KB

    const int tid  = threadIdx.x;
    const int lane = tid & 63;
    const int wave = tid >> 6;
    const int lm   = lane & 15;
    const int quad = lane >> 4;
    const int blk  = blockIdx.x;
    const int xcd  = blk & 7;
    const int slot = blk >> 3;              // 0..63
    const int by   = xcd * 8 + (slot & 7);  // 0..63
    const int bx   = slot >> 3;             // 0..7
    const int r0 = by * 16;
    const int c0 = bx * 128 + wave * 32;

    const u16* wswblk = wsw + (size_t)by * 65536;   // 4 chunks x 16384 shorts

    // ---- stage chunk 0 (async) ----
#pragma unroll
    for (int rr = 0; rr < 8; ++rr) {
        const int ub = wave * 4096 + rr * 512;   // shorts
        async_copy16(wswblk + ub + lane * 8, &wlds[0][ub]);
    }

    // ---- hoisted per-step loads: x -> vv -> Qp vectors; c state ----
    int vv[2];
#pragma unroll
    for (int nt = 0; nt < 2; ++nt) {
        int v = x[(size_t)(c0 + nt * 16 + lm) * kS + t];
        vv[nt] = (v < 0) ? 0 : (v > kV - 1) ? (kV - 1) : v;
    }
    f32x4 qv[2][4];
#pragma unroll
    for (int nt = 0; nt < 2; ++nt)
#pragma unroll
        for (int g = 0; g < 4; ++g)
            qv[nt][g] = *(const f32x4*)(Qp +
                (size_t)(((g * 256 + by * 4 + quad) * 4 + vv[nt]) * 4));
    f32x4 cold[2];
#pragma unroll
    for (int nt = 0; nt < 2; ++nt)
        cold[nt] = *(const f32x4*)(cT +
            (size_t)(c0 + nt * 16 + lm) * kH + r0 + quad * 4);

    // ---- b-ring prologue: slots 0..4 ----
    const int koff = quad * 8;
    const short* hrow0 = hin + (size_t)(c0 + lm) * kH + koff;
    const short* hrow1 = hin + (size_t)(c0 + 16 + lm) * kH + koff;
    s16x8 br[6][2];
#pragma unroll
    for (int s = 0; s < 5; ++s) {
        br[s][0] = *(const s16x8*)(hrow0 + s * 32);
        br[s][1] = *(const s16x8*)(hrow1 + s * 32);
    }

    f32x4 acc[4][2];
    const f32x4 zero = {0.f, 0.f, 0.f, 0.f};
#pragma unroll
    for (int g = 0; g < 4; ++g)
#pragma unroll
        for (int n = 0; n < 2; ++n) acc[g][n] = zero;

    asm volatile("s_waitcnt vmcnt(0)" ::: "memory");
    __syncthreads();

    // ---- main K loop: 32 x (4 ds_read + 8 MFMA), chunked staging ----
#pragma unroll
    for (int k0 = 0; k0 < 32; ++k0) {
        if ((k0 & 7) == 0 && k0 > 0) {
            // chunk k0/8 staged during previous chunk; drain + barrier
            asm volatile("s_waitcnt vmcnt(0)" ::: "memory");
            __syncthreads();
        }
        if ((k0 & 7) == 0 && k0 < 24) {
            const int nc = (k0 >> 3) + 1;
            const u16* gsrc = wswblk + (size_t)nc * 16384;
#pragma unroll
            for (int rr = 0; rr < 8; ++rr) {
                const int ub = wave * 4096 + rr * 512;
                async_copy16(gsrc + ub + lane * 8, &wlds[nc & 1][ub]);
            }
        }
        if (k0 + 5 < 32) {
            const int s = (k0 + 5) % 6;
            br[s][0] = *(const s16x8*)(hrow0 + (k0 + 5) * 32);
            br[s][1] = *(const s16x8*)(hrow1 + (k0 + 5) * 32);
        }
        const int cur = k0 % 6;
        const int buf = (k0 >> 3) & 1;
#pragma unroll
        for (int g = 0; g < 4; ++g) {
            const int f = ((g * 8 + (k0 & 7)) * 64 + lane) * 8;   // shorts
            s16x8 a = *(const s16x8*)&wlds[buf][f];
            acc[g][0] = __builtin_amdgcn_mfma_f32_16x16x32_bf16(a, br[cur][0], acc[g][0], 0, 0, 0);
            acc[g][1] = __builtin_amdgcn_mfma_f32_16x16x32_bf16(a, br[cur][1], acc[g][1], 0, 0, 0);
        }
    }

    // ---- epilogue: pure ALU + stores. C/D: col=lane&15, row=quad*4+reg ----
#pragma unroll
    for (int nt = 0; nt < 2; ++nt) {
        const int c = c0 + nt * 16 + lm;
        const int rb = r0 + quad * 4;
        f32x4 cnew;
        s16x4 hnew;
#pragma unroll
        for (int reg = 0; reg < 4; ++reg) {
            float pg = clamp30(acc[0][nt][reg] + qv[nt][0][reg]);
            float pi = clamp30(acc[1][nt][reg] + qv[nt][1][reg]);
            float pf = clamp30(acc[2][nt][reg] + qv[nt][2][reg]);
            float po = clamp30(acc[3][nt][reg] + qv[nt][3][reg]);
            float gg = tanh_fast(pg);
            float ii = sigmoid_fast(pi);
            float ff = sigmoid_fast(pf);
            float oo = sigmoid_fast(po);
            float c2 = gg * ii + cold[nt][reg] * ff;
            c2 = fminf(fmaxf(c2, -200.0f), 200.0f);
            cnew[reg] = c2;
            hnew[reg] = (short)f2b(tanh_fast(c2) * oo);
        }
        *(f32x4*)(cT + (size_t)c * kH + rb) = cnew;
        *(s16x4*)(hout + (size_t)c * kH + rb) = hnew;
    }
}

// ---------------------------------------------------------------------------
// Logits: p[b][cls] = h[b,:] . W_ph[cls,:] + b_p[cls]; log_softmax over 10.
// ---------------------------------------------------------------------------
__global__ __launch_bounds__(256) void logits_kernel(
    const u16* __restrict__ hT, const float* __restrict__ Wph,
    const float* __restrict__ bp, float* __restrict__ out)
{
    const int wave = threadIdx.x >> 6;
    const int lane = threadIdx.x & 63;
    const int b = blockIdx.x * 4 + wave;

    const u16* hp = hT + (size_t)b * kH + lane * 16;
    float hf[16];
#pragma unroll
    for (int j = 0; j < 16; ++j) hf[j] = b2f(hp[j]);

    float p[kC];
#pragma unroll
    for (int cls = 0; cls < kC; ++cls) {
        const float* wp = Wph + (size_t)cls * kH + lane * 16;
        float s = 0.f;
#pragma unroll
        for (int j = 0; j < 16; ++j) s += hf[j] * wp[j];
#pragma unroll
        for (int off = 1; off < 64; off <<= 1) s += __shfl_xor(s, off, 64);
        p[cls] = fminf(fmaxf(s + bp[cls], -1.0e4f), 1.0e4f);
    }

    float m = p[0];
#pragma unroll
    for (int cls = 1; cls < kC; ++cls) m = fmaxf(m, p[cls]);
    float se = 0.f;
#pragma unroll
    for (int cls = 0; cls < kC; ++cls) se += __expf(p[cls] - m);
    float l = m + __logf(se);

    if (lane < kC) {
        float myp = p[0];
#pragma unroll
        for (int cls = 1; cls < kC; ++cls)
            if (lane == cls) myp = p[cls];
        out[(size_t)b * kC + lane] = myp - l;
    }
}

// ---------------------------------------------------------------------------
extern "C" void kernel_launch(void* const* d_in, const int* in_sizes, int n_in,
                              void* d_out, int out_size, void* d_ws, size_t ws_size,
                              hipStream_t stream)
{
    const int*   x   = (const int*)  d_in[0];
    const float* emb = (const float*)d_in[1];
    const float* Wgx = (const float*)d_in[2];
    const float* Wgh = (const float*)d_in[3];
    const float* bg  = (const float*)d_in[4];
    const float* Wix = (const float*)d_in[5];
    const float* Wih = (const float*)d_in[6];
    const float* bi  = (const float*)d_in[7];
    const float* Wfx = (const float*)d_in[8];
    const float* Wfh = (const float*)d_in[9];
    const float* bf_ = (const float*)d_in[10];
    const float* Wox = (const float*)d_in[11];
    const float* Woh = (const float*)d_in[12];
    const float* bo  = (const float*)d_in[13];
    const float* Wph = (const float*)d_in[14];
    const float* bp  = (const float*)d_in[15];
    const float* h0  = (const float*)d_in[16];
    const float* c0  = (const float*)d_in[17];

    char* ws = (char*)d_ws;
    float* Qp  = (float*)ws;                              // 64 KB
    u16*   hA  = (u16*)(ws + (64 << 10));                 // 2 MB
    u16*   hB  = hA + (size_t)kB * kH;                    // 2 MB
    float* cT  = (float*)(hB + (size_t)kB * kH);          // 4 MB
    u16*   wsw = (u16*)(cT + (size_t)kB * kH);            // 8 MB  (total ~16.1 MB)

    prep_weights<<<dim3(2048), dim3(256), 0, stream>>>(Wgh, Wih, Wfh, Woh, wsw);
    prep_hc<<<dim3(kB / 32, kH / 32), dim3(32, 32), 0, stream>>>(h0, c0, hA, cT);
    prep_q<<<dim3(16), dim3(256), 0, stream>>>(Wgx, Wix, Wfx, Wox, bg, bi, bf_, bo, emb, Qp);

    for (int t = 0; t < kT; ++t) {
        const u16* hin  = (t & 1) ? hB : hA;
        u16*       hout = (t & 1) ? hA : hB;
        lstm_step<<<dim3(512), dim3(256), 0, stream>>>(
            wsw, Qp, x, t, (const short*)hin, hout, cT);
    }
    // 127 steps: t=126 (even) wrote hB.
    logits_kernel<<<dim3(kB / 4), dim3(256), 0, stream>>>(hB, Wph, bp, (float*)d_out);
}